// Round 10
// baseline (30.453 us; speedup 1.0000x reference)
//
#include <hip/hip_runtime.h>
#include <math.h>

extern "C" __device__ float __ocml_native_log2_f32(float);
extern "C" __device__ float __ocml_native_exp2_f32(float);
#define FAST_LOG2(x) __ocml_native_log2_f32(x)
#define FAST_EXP2(x) __ocml_native_exp2_f32(x)

#define NBV   512              // vocab-scan blocks
#define NPREP 32               // row-scan blocks
#define MSTR  132              // per-block vocab partial stride (128 M + Z + A + pad)
// ws float layout:
//   [b*MSTR .. b*MSTR+130)  vocab block b: M[0..127], Z, A   (contiguous!)
//   [SOFF + c*128 ...)      S_in partial of row-block c
//   [QOFF + c]              Q partial of row-block c
#define SOFF (NBV * MSTR)
#define QOFF (SOFF + NPREP * 128)
#define LOG2E 1.44269504f
#define LN2   0.69314718f

// 544 blocks x 256 threads, two independent roles (concurrent):
//   blocks [0,NBV):          vocab scan -> per-block M[128]/Z/A, contiguous
//   blocks [NBV,NBV+NPREP):  row scan   -> S_in partial + Q partial
// All plain disjoint stores; visibility via kernel boundary. No atomics/fences.
__global__ __launch_bounds__(256) void k_scan(const float* __restrict__ f,
        const float4* __restrict__ Eout4, const float* __restrict__ pred,
        const float4* __restrict__ Ein4, const int* __restrict__ xi,
        const int* __restrict__ yi, float* __restrict__ ws, int V, int n) {
    int t = threadIdx.x, lane = t & 31, sub = t >> 5;
    int b = blockIdx.x;
    __shared__ float4 sm[256];
    __shared__ float s1[8], s2[8];

    if (b < NBV) {
        // ---- vocab scan: f^0.75-weighted E_out sum, unroll-2 chains ----
        float4 m0 = {0.f,0.f,0.f,0.f}, m1 = {0.f,0.f,0.f,0.f};
        float zp = 0.f, ap = 0.f;
        const int S = NBV * 8;                      // 4096 rows per half-sweep
        for (int v = b * 8 + sub; v < V; v += 2 * S) {
            {   // chain 0
                float l2 = FAST_LOG2(f[v]);         // v_log_f32
                float p  = FAST_EXP2(0.75f * l2);   // v_exp_f32 : f^0.75
                float4 e = Eout4[(size_t)v * 32 + lane];
                m0.x = fmaf(p, e.x, m0.x); m0.y = fmaf(p, e.y, m0.y);
                m0.z = fmaf(p, e.z, m0.z); m0.w = fmaf(p, e.w, m0.w);
                if (lane == 0) { zp += p; ap = fmaf(p, 0.75f * l2 * LN2, ap); }
            }
            int v1 = v + S;
            if (v1 < V) {   // chain 1 (independent)
                float l2 = FAST_LOG2(f[v1]);
                float p  = FAST_EXP2(0.75f * l2);
                float4 e = Eout4[(size_t)v1 * 32 + lane];
                m1.x = fmaf(p, e.x, m1.x); m1.y = fmaf(p, e.y, m1.y);
                m1.z = fmaf(p, e.z, m1.z); m1.w = fmaf(p, e.w, m1.w);
                if (lane == 0) { zp += p; ap = fmaf(p, 0.75f * l2 * LN2, ap); }
            }
        }
        m0.x += m1.x; m0.y += m1.y; m0.z += m1.z; m0.w += m1.w;
        sm[t] = m0;
        if (lane == 0) { s1[sub] = zp; s2[sub] = ap; }
        __syncthreads();
        if (t < 32) {
            float4 a = sm[t];
            #pragma unroll
            for (int s = 1; s < 8; ++s) {
                float4 q = sm[s * 32 + t];
                a.x += q.x; a.y += q.y; a.z += q.z; a.w += q.w;
            }
            // contiguous 512B burst: pm[b][t*4 .. t*4+3]
            ((float4*)(ws + (size_t)b * MSTR))[t] = a;
        } else if (t == 32) {
            float z = 0.f, a = 0.f;
            #pragma unroll
            for (int s = 0; s < 8; ++s) { z += s1[s]; a += s2[s]; }
            ws[(size_t)b * MSTR + 128] = z;
            ws[(size_t)b * MSTR + 129] = a;
        }
    } else {
        // ---- row scan: S_in partial + Q partial ----
        int c = b - NBV;                       // 0..31
        int rpb = (n + NPREP - 1) / NPREP;     // 64 for n=2048
        int r0 = c * rpb, r1 = min(r0 + rpb, n);
        float4 acc = {0.f, 0.f, 0.f, 0.f};
        float q = 0.f;
        for (int r = r0 + sub; r < r1; r += 8) {
            int x = xi[r];
            float4 e = Ein4[(size_t)x * 32 + lane];
            acc.x += e.x; acc.y += e.y; acc.z += e.z; acc.w += e.w;
            if (lane == 0) {
                // softplus(-z_pos)=exp(-z_pos) to ~1e-32 (z_pos >= ~45);
                // exp(-z_pos)*Z^5 = f[y]^3.75 * exp(-pred)
                q += FAST_EXP2(fmaf(3.75f, FAST_LOG2(f[yi[r]]), -pred[r] * LOG2E));
            }
        }
        sm[t] = acc;
        if (lane == 0) s1[sub] = q;
        __syncthreads();
        if (t < 32) {
            float4 a = sm[t];
            #pragma unroll
            for (int s = 1; s < 8; ++s) {
                float4 v = sm[s * 32 + t];
                a.x += v.x; a.y += v.y; a.z += v.z; a.w += v.w;
            }
            ((float4*)(ws + SOFF))[c * 32 + t] = a;
        } else if (t == 32) {
            float z = 0.f;
            #pragma unroll
            for (int s = 0; s < 8; ++s) z += s1[s];
            ws[QOFF + c] = z;
        }
    }
}

// 1 block x 1024 threads: transpose-reduce [NBV][MSTR] partials (coalesced),
// reduce S_in/Q partials, DOT = <M, S_in>, finalize scalar.
__global__ __launch_bounds__(1024) void k_fin(const float* __restrict__ ws,
                                              float* __restrict__ out, int n) {
    int t = threadIdx.x;
    __shared__ float red[8][128];
    __shared__ float sM[128], sS[128], sZA[2], sQ[1];

    // M components: group g = t>>7 (0..7) covers blocks g, g+8, ...; c = t&127.
    // Reads of pm[b][0..127] are contiguous across the 128 threads of a group.
    int g = t >> 7, c = t & 127;
    float s = 0.f;
    for (int b = g; b < NBV; b += 8) s += ws[(size_t)b * MSTR + c];
    red[g][c] = s;
    __syncthreads();
    if (t < 128) {
        float m = 0.f;
        #pragma unroll
        for (int i = 0; i < 8; ++i) m += red[i][t];
        sM[t] = m;
        float q = 0.f;
        #pragma unroll
        for (int p = 0; p < NPREP; ++p) q += ws[SOFF + p * 128 + t];
        sS[t] = q;
    } else if (t < 192) {              // wave 2: Z
        int l = t - 128;
        float z = 0.f;
        for (int b = l; b < NBV; b += 64) z += ws[(size_t)b * MSTR + 128];
        #pragma unroll
        for (int off = 32; off; off >>= 1) z += __shfl_down(z, off);
        if (l == 0) sZA[0] = z;
    } else if (t < 256) {              // wave 3: A
        int l = t - 192;
        float a = 0.f;
        for (int b = l; b < NBV; b += 64) a += ws[(size_t)b * MSTR + 129];
        #pragma unroll
        for (int off = 32; off; off >>= 1) a += __shfl_down(a, off);
        if (l == 0) sZA[1] = a;
    } else if (t < 320) {              // wave 4: Q
        int l = t - 256;
        float q = (l < NPREP) ? ws[QOFF + l] : 0.f;
        #pragma unroll
        for (int off = 32; off; off >>= 1) q += __shfl_down(q, off);
        if (l == 0) sQ[0] = q;
    }
    __syncthreads();
    if (t < 64) {
        float d = sM[t] * sS[t] + sM[t + 64] * sS[t + 64];
        #pragma unroll
        for (int off = 32; off; off >>= 1) d += __shfl_down(d, off);
        if (t == 0) {
            float Z    = sZA[0];
            float A    = sZA[1];
            float Q    = sQ[0];
            float logZ = logf(Z);
            float H    = logZ - A / Z;                  // E_dist[-log dist]
            float invn = 1.f / (float)n;
            float pos  = Q * expf(-5.f * logZ) * invn;  // mean softplus(-z_pos)
            float negd = 5.f * (d / Z) * invn;          // 5 * mean <E_in[x], m>
            out[0] = pos + negd + 25.f * H;             // pos + 5*neg_loss
        }
    }
}

extern "C" void kernel_launch(void* const* d_in, const int* in_sizes, int n_in,
                              void* d_out, int out_size, void* d_ws, size_t ws_size,
                              hipStream_t stream) {
    const float*  f    = (const float*)d_in[0];    // word_freqs [V]
    const float*  pred = (const float*)d_in[1];    // [n]
    const float4* Ein4 = (const float4*)d_in[2];   // [V,128] as [V,32] float4
    const float4* Eout4= (const float4*)d_in[3];
    const int*    xi   = (const int*)d_in[4];
    const int*    yi   = (const int*)d_in[5];
    int V = in_sizes[0];
    int n = in_sizes[1];
    float* ws  = (float*)d_ws;
    float* out = (float*)d_out;

    k_scan<<<NBV + NPREP, 256, 0, stream>>>(f, Eout4, pred, Ein4, xi, yi, ws, V, n);
    k_fin <<<1, 1024, 0, stream>>>(ws, out, n);
}

// Round 11
// 17.447 us; speedup vs baseline: 1.7455x; 1.7455x over previous
//
#include <hip/hip_runtime.h>
#include <math.h>

extern "C" __device__ float __ocml_native_log2_f32(float);
extern "C" __device__ float __ocml_native_exp2_f32(float);
#define FAST_LOG2(x) __ocml_native_log2_f32(x)
#define FAST_EXP2(x) __ocml_native_exp2_f32(x)

#define NPREP 32               // row-scan blocks
#define NB    512              // vocab-scan blocks
// ws float layout:
//   [0 .. NPREP*128)        S_in partials (partial c at [c*128, c*128+128))
//   [QOFF .. QOFF+NPREP)    Q partials (pos-term numerator)
//   [DOFF + 0*NB + b]       dot partial of vocab block b
//   [DOFF + 1*NB + b]       Z partial
//   [DOFF + 2*NB + b]       A partial (sum p * ln p)
#define QOFF (NPREP * 128)
#define DOFF (QOFF + NPREP)
#define LOG2E 1.44269504f
#define LN2   0.69314718f

// 32 blocks x 256 threads: S_in partial = sum of E_in[x_r] over this block's
// rows; Q partial = sum exp(-z_pos) * Z^5  (softplus(-z)=exp(-z) to ~1e-32).
__global__ __launch_bounds__(256) void kA(const float* __restrict__ f,
        const float* __restrict__ pred, const float4* __restrict__ Ein4,
        const int* __restrict__ xi, const int* __restrict__ yi,
        float* __restrict__ ws, int n) {
    int t = threadIdx.x, lane = t & 31, sub = t >> 5;
    int c = blockIdx.x;
    int rpb = (n + NPREP - 1) / NPREP;           // 64 for n=2048
    int r0 = c * rpb, r1 = min(r0 + rpb, n);
    float4 acc = {0.f, 0.f, 0.f, 0.f};
    float q = 0.f;
    for (int r = r0 + sub; r < r1; r += 8) {
        int x = xi[r];
        float4 e = Ein4[(size_t)x * 32 + lane];
        acc.x += e.x; acc.y += e.y; acc.z += e.z; acc.w += e.w;
        if (lane == 0) {
            // exp(-z_pos)*Z^5 = f[y]^3.75 * exp(-pred) = 2^(3.75*log2 f - pred*log2e)
            q += FAST_EXP2(fmaf(3.75f, FAST_LOG2(f[yi[r]]), -pred[r] * LOG2E));
        }
    }
    __shared__ float4 sm[256];
    __shared__ float sq[8];
    sm[t] = acc;
    if (lane == 0) sq[sub] = q;
    __syncthreads();
    if (t < 32) {
        float4 a = sm[t];
        #pragma unroll
        for (int s = 1; s < 8; ++s) {
            float4 v = sm[s * 32 + t];
            a.x += v.x; a.y += v.y; a.z += v.z; a.w += v.w;
        }
        ((float4*)ws)[c * 32 + t] = a;
    } else if (t == 32) {
        float z = 0.f;
        #pragma unroll
        for (int s = 0; s < 8; ++s) z += sq[s];
        ws[QOFF + c] = z;
    }
}

// 512 blocks x 256 threads: rebuild S_in into LDS, vocab scan with FOUR
// independent chains per iteration (deep MLP), scalars dot/Z/A out.
__global__ __launch_bounds__(256) void kB(const float* __restrict__ f,
        const float4* __restrict__ Eout4, float* __restrict__ ws, int V) {
    int t = threadIdx.x, lane = t & 31, sub = t >> 5;
    int b = blockIdx.x;
    __shared__ float sS2[2][128];
    {   // all 256 threads rebuild: half h sums partials [h*16, h*16+16)
        int h = t >> 7, comp = t & 127;
        float s = 0.f;
        #pragma unroll
        for (int c = 0; c < NPREP / 2; ++c) s += ws[(h * (NPREP / 2) + c) * 128 + comp];
        sS2[h][comp] = s;
    }
    __syncthreads();
    float4 s4 = { sS2[0][lane*4+0] + sS2[1][lane*4+0],
                  sS2[0][lane*4+1] + sS2[1][lane*4+1],
                  sS2[0][lane*4+2] + sS2[1][lane*4+2],
                  sS2[0][lane*4+3] + sS2[1][lane*4+3] };

    float d0=0.f, d1=0.f, d2=0.f, d3=0.f, zp=0.f, ap=0.f;
    const int S = NB * 8;                        // 4096 rows per quarter-sweep
    for (int v = b * 8 + sub; v < V; v += 4 * S) {
        {   // chain 0 (always valid)
            float l2 = FAST_LOG2(f[v]);
            float p  = FAST_EXP2(0.75f * l2);
            float4 e = Eout4[(size_t)v * 32 + lane];
            float dd = e.x*s4.x + e.y*s4.y + e.z*s4.z + e.w*s4.w;
            d0 = fmaf(p, dd, d0);
            if (lane == 0) { zp += p; ap = fmaf(p, 0.75f * l2 * LN2, ap); }
        }
        int v1 = v + S;
        if (v1 < V) {
            float l2 = FAST_LOG2(f[v1]);
            float p  = FAST_EXP2(0.75f * l2);
            float4 e = Eout4[(size_t)v1 * 32 + lane];
            float dd = e.x*s4.x + e.y*s4.y + e.z*s4.z + e.w*s4.w;
            d1 = fmaf(p, dd, d1);
            if (lane == 0) { zp += p; ap = fmaf(p, 0.75f * l2 * LN2, ap); }
        }
        int v2 = v + 2 * S;
        if (v2 < V) {
            float l2 = FAST_LOG2(f[v2]);
            float p  = FAST_EXP2(0.75f * l2);
            float4 e = Eout4[(size_t)v2 * 32 + lane];
            float dd = e.x*s4.x + e.y*s4.y + e.z*s4.z + e.w*s4.w;
            d2 = fmaf(p, dd, d2);
            if (lane == 0) { zp += p; ap = fmaf(p, 0.75f * l2 * LN2, ap); }
        }
        int v3 = v + 3 * S;
        if (v3 < V) {
            float l2 = FAST_LOG2(f[v3]);
            float p  = FAST_EXP2(0.75f * l2);
            float4 e = Eout4[(size_t)v3 * 32 + lane];
            float dd = e.x*s4.x + e.y*s4.y + e.z*s4.z + e.w*s4.w;
            d3 = fmaf(p, dd, d3);
            if (lane == 0) { zp += p; ap = fmaf(p, 0.75f * l2 * LN2, ap); }
        }
    }
    float d = (d0 + d1) + (d2 + d3), z = zp, a = ap;
    #pragma unroll
    for (int off = 32; off; off >>= 1) {
        d += __shfl_xor(d, off);
        z += __shfl_xor(z, off);
        a += __shfl_xor(a, off);
    }
    __shared__ float sw[4][3];
    int wid = t >> 6;
    if ((t & 63) == 0) { sw[wid][0] = d; sw[wid][1] = z; sw[wid][2] = a; }
    __syncthreads();
    if (t == 0) {
        float D = 0.f, Z = 0.f, A = 0.f;
        #pragma unroll
        for (int w = 0; w < 4; ++w) { D += sw[w][0]; Z += sw[w][1]; A += sw[w][2]; }
        ws[DOFF + b]          = D;
        ws[DOFF + NB + b]     = Z;
        ws[DOFF + 2 * NB + b] = A;
    }
}

// 1 block x 256 threads: reduce 3*NB + NPREP partials, final scalar math.
__global__ __launch_bounds__(256) void kC(const float* __restrict__ ws,
                                          float* __restrict__ out, int n) {
    int t = threadIdx.x;
    float d = 0.f, z = 0.f, a = 0.f, q = 0.f;
    for (int i = t; i < NB; i += 256) {
        d += ws[DOFF + i];
        z += ws[DOFF + NB + i];
        a += ws[DOFF + 2 * NB + i];
    }
    if (t < NPREP) q = ws[QOFF + t];
    #pragma unroll
    for (int off = 32; off; off >>= 1) {
        d += __shfl_xor(d, off);
        z += __shfl_xor(z, off);
        a += __shfl_xor(a, off);
        q += __shfl_xor(q, off);
    }
    __shared__ float sm[4][4];
    int wid = t >> 6;
    if ((t & 63) == 0) { sm[wid][0]=d; sm[wid][1]=z; sm[wid][2]=a; sm[wid][3]=q; }
    __syncthreads();
    if (t == 0) {
        float D=0.f, Z=0.f, A=0.f, Q=0.f;
        #pragma unroll
        for (int w = 0; w < 4; ++w) { D+=sm[w][0]; Z+=sm[w][1]; A+=sm[w][2]; Q+=sm[w][3]; }
        float logZ = logf(Z);
        float H    = logZ - A / Z;                  // E_dist[-log dist]
        float invn = 1.f / (float)n;
        float pos  = Q * expf(-5.f * logZ) * invn;  // mean softplus(-z_pos)
        float negd = 5.f * (D / Z) * invn;          // 5 * mean <E_in[x], m>
        out[0] = pos + negd + 25.f * H;             // pos + 5*neg_loss
    }
}

extern "C" void kernel_launch(void* const* d_in, const int* in_sizes, int n_in,
                              void* d_out, int out_size, void* d_ws, size_t ws_size,
                              hipStream_t stream) {
    const float*  f    = (const float*)d_in[0];    // word_freqs [V]
    const float*  pred = (const float*)d_in[1];    // [n]
    const float4* Ein4 = (const float4*)d_in[2];   // [V,128] as [V,32] float4
    const float4* Eout4= (const float4*)d_in[3];
    const int*    xi   = (const int*)d_in[4];
    const int*    yi   = (const int*)d_in[5];
    int V = in_sizes[0];
    int n = in_sizes[1];
    float* ws  = (float*)d_ws;
    float* out = (float*)d_out;

    kA<<<NPREP, 256, 0, stream>>>(f, pred, Ein4, xi, yi, ws, n);
    kB<<<NB, 256, 0, stream>>>(f, Eout4, ws, V);
    kC<<<1, 256, 0, stream>>>(ws, out, n);
}